// Round 8
// baseline (182.109 us; speedup 1.0000x reference)
//
#include <hip/hip_runtime.h>

#define HID 20

// Scalar SiLU via native exp2/rcp. Same per-lane formula/op-order as all
// prior rounds -> bit-identical results (absmax 0.0).
__device__ __forceinline__ float si(float a) {
    float e = __builtin_amdgcn_exp2f(-1.442695040888963f * a);
    return a * __builtin_amdgcn_rcpf(1.0f + e);
}

// 20->20 layer on ONE point, j-blocked by 4 (4 independent acc chains --
// the best-measured inner structure, R1). Weights via wave-uniform global
// pointers -> SGPR s_load bursts, K$-resident.
// R8 rationale: the compiler fissions multi-point threads into sequential
// per-point passes anyway (VGPR=44 across R0-R7), so multi-point buys no
// ILP -- it only inflates the live set past the 64-VGPR/8-wave budget.
// 1 point/thread halves per-wave work, doubles wave count (16384 waves),
// and fits ~50 VGPR -> 8 waves/SIMD under (256,8). TLP, not ILP, covers
// the s_load waits and trans chains that were the 25% idle.
__device__ __forceinline__ void layer20_1(const float* __restrict__ W,
                                          const float* __restrict__ b,
                                          const float* __restrict__ h,
                                          float* __restrict__ o) {
    #pragma unroll
    for (int jb = 0; jb < HID; jb += 4) {
        float a0 = b[jb], a1 = b[jb + 1], a2 = b[jb + 2], a3 = b[jb + 3];
        #pragma unroll
        for (int i = 0; i < HID; ++i) {
            float x = h[i];
            a0 = __builtin_fmaf(x, W[(jb + 0) * HID + i], a0);
            a1 = __builtin_fmaf(x, W[(jb + 1) * HID + i], a1);
            a2 = __builtin_fmaf(x, W[(jb + 2) * HID + i], a2);
            a3 = __builtin_fmaf(x, W[(jb + 3) * HID + i], a3);
        }
        o[jb] = si(a0); o[jb + 1] = si(a1); o[jb + 2] = si(a2); o[jb + 3] = si(a3);
    }
}

// (256,8): 64-VGPR regalloc budget. 1-pt live set: h(20)+o-forming(<=16)+
// 4 acc + temps ~ 45-55 VGPR -> no spill expected. Tripwire: WRITE_SIZE
// must stay ~4MB (spill signature was R4/R5's 64-284MB).
__global__ __launch_bounds__(256, 8) void SpringEquationNN_70102456205450_kernel(
    const float* __restrict__ t,
    const float* __restrict__ W0, const float* __restrict__ b0,
    const float* __restrict__ W1, const float* __restrict__ b1,
    const float* __restrict__ W2, const float* __restrict__ b2,
    const float* __restrict__ W3, const float* __restrict__ b3,
    const float* __restrict__ W4, const float* __restrict__ b4,
    const float* __restrict__ W5, const float* __restrict__ b5,
    const float* __restrict__ W6, const float* __restrict__ b6,
    const float* __restrict__ W7, const float* __restrict__ b7,
    float* __restrict__ out, int n)
{
    int idx = blockIdx.x * blockDim.x + threadIdx.x;   // point index
    if (idx >= n) return;

    float x = t[idx];   // 4B/lane, coalesced

    float h[HID], g[HID];

    // Layer 0: 1 -> 20
    #pragma unroll
    for (int j = 0; j < HID; ++j)
        h[j] = si(__builtin_fmaf(x, W0[j], b0[j]));

    // Layers 1..6: 20 -> 20, SiLU (ping-pong, ends in h)
    layer20_1(W1, b1, h, g);
    layer20_1(W2, b2, g, h);
    layer20_1(W3, b3, h, g);
    layer20_1(W4, b4, g, h);
    layer20_1(W5, b5, h, g);
    layer20_1(W6, b6, g, h);

    // Layer 7: 20 -> 1, serial ascending-i chain (exact reference order).
    float acc = b7[0];
    #pragma unroll
    for (int i = 0; i < HID; ++i)
        acc = __builtin_fmaf(h[i], W7[i], acc);

    out[idx] = acc;   // 4B/lane, coalesced
}

extern "C" void kernel_launch(void* const* d_in, const int* in_sizes, int n_in,
                              void* d_out, int out_size, void* d_ws, size_t ws_size,
                              hipStream_t stream) {
    const float* t  = (const float*)d_in[0];
    const float* W0 = (const float*)d_in[1];
    const float* b0 = (const float*)d_in[2];
    const float* W1 = (const float*)d_in[3];
    const float* b1 = (const float*)d_in[4];
    const float* W2 = (const float*)d_in[5];
    const float* b2 = (const float*)d_in[6];
    const float* W3 = (const float*)d_in[7];
    const float* b3 = (const float*)d_in[8];
    const float* W4 = (const float*)d_in[9];
    const float* b4 = (const float*)d_in[10];
    const float* W5 = (const float*)d_in[11];
    const float* b5 = (const float*)d_in[12];
    const float* W6 = (const float*)d_in[13];
    const float* b6 = (const float*)d_in[14];
    const float* W7 = (const float*)d_in[15];
    const float* b7 = (const float*)d_in[16];
    float* out = (float*)d_out;

    int n = in_sizes[0];             // N points (1048576)
    int block = 256;
    int grid = (n + block - 1) / block;
    SpringEquationNN_70102456205450_kernel<<<grid, block, 0, stream>>>(
        t, W0, b0, W1, b1, W2, b2, W3, b3, W4, b4, W5, b5, W6, b6, W7, b7,
        out, n);
}

// Round 9
// 152.002 us; speedup vs baseline: 1.1981x; 1.1981x over previous
//
#include <hip/hip_runtime.h>

#define HID 20

typedef float v2f __attribute__((ext_vector_type(2)));

// Native-instruction SiLU on a packed pair. exp/rcp are scalar trans ops
// (quarter-rate); surrounding muls pack. Formula bit-identical to all rounds.
__device__ __forceinline__ v2f silu2(v2f a) {
    v2f s = a * (-1.442695040888963f);
    float e0 = __builtin_amdgcn_exp2f(s.x);
    float e1 = __builtin_amdgcn_exp2f(s.y);
    v2f rc;
    rc.x = __builtin_amdgcn_rcpf(1.0f + e0);
    rc.y = __builtin_amdgcn_rcpf(1.0f + e1);
    return a * rc;
}

// 20->20 layer on a pair of points, j-blocked by 4 (R1's proven structure:
// 4 independent acc chains, SGPR weight bursts, 60us busy-cycle stream).
template <int JB>
__device__ __forceinline__ void layer20(const float* __restrict__ W,
                                        const float* __restrict__ b,
                                        const v2f* __restrict__ h,
                                        v2f* __restrict__ hn) {
    static_assert(HID % JB == 0, "JB must divide HID");
    #pragma unroll
    for (int jb = 0; jb < HID; jb += JB) {
        v2f acc[JB];
        #pragma unroll
        for (int j = 0; j < JB; ++j) {
            float bj = b[jb + j];
            acc[j] = (v2f){bj, bj};
        }
        #pragma unroll
        for (int i = 0; i < HID; ++i) {
            v2f hi = h[i];
            #pragma unroll
            for (int j = 0; j < JB; ++j) {
                float w = W[(jb + j) * HID + i];
                acc[j] = __builtin_elementwise_fma(hi, (v2f){w, w}, acc[j]);
            }
        }
        #pragma unroll
        for (int j = 0; j < JB; ++j)
            hn[jb + j] = silu2(acc[j]);
    }
}

// R9 change vs R1 (83us best): layers 1-6 in a NON-UNROLLED loop (3 x 2
// layers). Theory: fully-unrolled 2-pt code is ~46KB straight-line -- 1.4x
// the 32KB I$; every 2-pt variant (R1/R2/R3/R7, all ~46KB) is pinned at
// 64-74% duty, while the only I$-fitting kernel (R8, 23KB) hit 89% duty.
// Looping shrinks code ~3x to ~15KB (fits I$) while keeping R1's exact
// per-point instruction stream. Layer pointers selected by wave-uniform
// scalar branches (cheap s_cselect); ping-pong preserved by 2-layer pairs.
__global__ __launch_bounds__(256, 4) void SpringEquationNN_70102456205450_kernel(
    const float* __restrict__ t,
    const float* __restrict__ W0, const float* __restrict__ b0,
    const float* __restrict__ W1, const float* __restrict__ b1,
    const float* __restrict__ W2, const float* __restrict__ b2,
    const float* __restrict__ W3, const float* __restrict__ b3,
    const float* __restrict__ W4, const float* __restrict__ b4,
    const float* __restrict__ W5, const float* __restrict__ b5,
    const float* __restrict__ W6, const float* __restrict__ b6,
    const float* __restrict__ W7, const float* __restrict__ b7,
    float* __restrict__ out, int n)
{
    int idx = blockIdx.x * blockDim.x + threadIdx.x;   // pair index
    int p0 = 2 * idx;
    if (p0 >= n) return;

    // Coalesced 8B load of two consecutive points (N is even: 1048576).
    v2f x = *(const v2f*)(t + p0);

    v2f h[HID], hn[HID];

    // Layer 0: 1 -> 20 on both points
    #pragma unroll
    for (int j = 0; j < HID; ++j) {
        float w = W0[j], bb = b0[j];
        v2f a = __builtin_elementwise_fma(x, (v2f){w, w}, (v2f){bb, bb});
        h[j] = silu2(a);
    }

    // Layers 1..6 as 3 iterations x (2 layers). MUST NOT unroll (code size).
    #pragma unroll 1
    for (int it = 0; it < 3; ++it) {
        const float *Wa, *ba_, *Wb, *bb_;
        if (it == 0)      { Wa = W1; ba_ = b1; Wb = W2; bb_ = b2; }
        else if (it == 1) { Wa = W3; ba_ = b3; Wb = W4; bb_ = b4; }
        else              { Wa = W5; ba_ = b5; Wb = W6; bb_ = b6; }
        layer20<4>(Wa, ba_, h, hn);
        layer20<4>(Wb, bb_, hn, h);
    }

    // Layer 7: 20 -> 1 (no activation). Serial ascending-i chain preserves
    // the exact reference summation order.
    float b7v = b7[0];
    v2f acc = {b7v, b7v};
    #pragma unroll
    for (int i = 0; i < HID; ++i) {
        float w = W7[i];
        acc = __builtin_elementwise_fma(h[i], (v2f){w, w}, acc);
    }

    // Coalesced 8B store.
    *(v2f*)(out + p0) = acc;
}

extern "C" void kernel_launch(void* const* d_in, const int* in_sizes, int n_in,
                              void* d_out, int out_size, void* d_ws, size_t ws_size,
                              hipStream_t stream) {
    const float* t  = (const float*)d_in[0];
    const float* W0 = (const float*)d_in[1];
    const float* b0 = (const float*)d_in[2];
    const float* W1 = (const float*)d_in[3];
    const float* b1 = (const float*)d_in[4];
    const float* W2 = (const float*)d_in[5];
    const float* b2 = (const float*)d_in[6];
    const float* W3 = (const float*)d_in[7];
    const float* b3 = (const float*)d_in[8];
    const float* W4 = (const float*)d_in[9];
    const float* b4 = (const float*)d_in[10];
    const float* W5 = (const float*)d_in[11];
    const float* b5 = (const float*)d_in[12];
    const float* W6 = (const float*)d_in[13];
    const float* b6 = (const float*)d_in[14];
    const float* W7 = (const float*)d_in[15];
    const float* b7 = (const float*)d_in[16];
    float* out = (float*)d_out;

    int n = in_sizes[0];             // N points
    int pairs = (n + 1) / 2;         // threads (N=1048576 -> 524288)
    int block = 256;
    int grid = (pairs + block - 1) / block;
    SpringEquationNN_70102456205450_kernel<<<grid, block, 0, stream>>>(
        t, W0, b0, W1, b1, W2, b2, W3, b3, W4, b4, W5, b5, W6, b6, W7, b7,
        out, n);
}